// Round 6
// baseline (415.250 us; speedup 1.0000x reference)
//
#include <hip/hip_runtime.h>
#include <hip/hip_bf16.h>

constexpr int Bc  = 1024;
constexpr int Vc  = 6890;
constexpr int Pc  = 24;
constexpr int SDc = 10;
constexpr int NJ  = Pc - 1;          // 23 rotated joints
constexpr int NC  = SDc + 9 * NJ;    // 217 coefficients
constexpr int V3  = 3 * Vc;          // 20670
constexpr int XD  = SDc + 3 * NJ;    // 79 input dims per batch
constexpr int BB  = 16;              // batches per block in skin kernel

// ws layout (in floats):
//   [0, 792)                 : JS[d][p][c] (720, d<SD) then Jt[p][c] (72)
//   [1024, 1024+NC*B)        : coefT [NC][B]   (transposed for uniform vec s_load)
//   [ROT_OFF, +B*P*12)       : rotdata [B][P][12] = rot(9, row-major) + t_adj(3)
constexpr size_t JS_OFF   = 0;
constexpr size_t COEF_OFF = 1024;
constexpr size_t ROT_OFF  = COEF_OFF + (size_t)NC * Bc;

// ---------------- Kernel A: batch-independent joint-regressor fold ----------
// JS[d][p][c] = sum_v j_reg[p][v] * s_mat[d][3v+c]   (d < SD)
// Jt[p][c]    = sum_v j_reg[p][v] * v_tmpl[3v+c]
__global__ __launch_bounds__(256) void lbs_prep_kernel(
    const float* __restrict__ s_mat, const float* __restrict__ v_tmpl,
    const float* __restrict__ j_reg, float* __restrict__ ws) {
  const int d = blockIdx.x;            // 0..SD   (SD => v_tmpl row)
  const int p = blockIdx.y;            // 0..P-1
  const float* src = (d < SDc) ? (s_mat + (size_t)d * V3) : v_tmpl;
  const float* jr  = j_reg + (size_t)p * Vc;
  float a0 = 0.f, a1 = 0.f, a2 = 0.f;
  for (int v = threadIdx.x; v < Vc; v += 256) {
    float w = jr[v];
    a0 += w * src[3 * v + 0];
    a1 += w * src[3 * v + 1];
    a2 += w * src[3 * v + 2];
  }
  // wave reduce (64 lanes), then cross-wave via LDS
  for (int off = 32; off > 0; off >>= 1) {
    a0 += __shfl_down(a0, off);
    a1 += __shfl_down(a1, off);
    a2 += __shfl_down(a2, off);
  }
  __shared__ float red[3][4];
  const int lane = threadIdx.x & 63, wid = threadIdx.x >> 6;
  if (lane == 0) { red[0][wid] = a0; red[1][wid] = a1; red[2][wid] = a2; }
  __syncthreads();
  if (threadIdx.x == 0) {
    float r0 = red[0][0] + red[0][1] + red[0][2] + red[0][3];
    float r1 = red[1][0] + red[1][1] + red[1][2] + red[1][3];
    float r2 = red[2][0] + red[2][1] + red[2][2] + red[2][3];
    float* dst = (d < SDc) ? (ws + ((size_t)d * Pc + p) * 3)
                           : (ws + 720 + (size_t)p * 3);
    dst[0] = r0; dst[1] = r1; dst[2] = r2;
  }
}

// ---------------- Kernel B: per-batch rodrigues + kinematic chain ----------
__global__ __launch_bounds__(256) void lbs_chain_kernel(
    const float* __restrict__ x, const float* __restrict__ ws_js,
    float* __restrict__ coefT, float* __restrict__ rotdata) {
  const int b = blockIdx.x * 256 + threadIdx.x;
  if (b >= Bc) return;
  const float* xb = x + (size_t)b * XD;

  // Joint locations: J[p][c] = sum_d x[d]*JS[d][p][c] + Jt[p][c]
  float J[Pc][3];
  for (int p = 0; p < Pc; ++p)
    for (int c = 0; c < 3; ++c) {
      float acc = ws_js[720 + p * 3 + c];
      for (int d = 0; d < SDc; ++d) acc += xb[d] * ws_js[((size_t)d * Pc + p) * 3 + c];
      J[p][c] = acc;
    }

  // coef (transposed layout [NC][B]): first SD entries are shape coeffs
  for (int d = 0; d < SDc; ++d) coefT[(size_t)d * Bc + b] = xb[d];

  float rot[3][3] = {{1, 0, 0}, {0, 1, 0}, {0, 0, 1}};
  float tr[3] = {J[0][0], J[0][1], J[0][2]};
  float* rd = rotdata + (size_t)b * Pc * 12;
  // node 0: rot = I, t_adj = tr - J0 @ I = 0
  rd[0] = 1; rd[1] = 0; rd[2] = 0;
  rd[3] = 0; rd[4] = 1; rd[5] = 0;
  rd[6] = 0; rd[7] = 0; rd[8] = 1;
  rd[9] = 0; rd[10] = 0; rd[11] = 0;

  for (int i = 0; i < NJ; ++i) {
    const int n = i + 1;
    // Rodrigues
    float r0 = xb[SDc + 3 * i + 0], r1 = xb[SDc + 3 * i + 1], r2 = xb[SDc + 3 * i + 2];
    float th = sqrtf(r0 * r0 + r1 * r1 + r2 * r2);
    float inv = 1.0f / fmaxf(th, 1e-8f);
    float n0 = r0 * inv, n1 = r1 * inv, n2 = r2 * inv;
    float cth = cosf(th), sth = sinf(th), omc = 1.0f - cth;
    float R[3][3];
    R[0][0] = cth + omc * n0 * n0;       R[0][1] = omc * n0 * n1 - sth * n2;  R[0][2] = omc * n0 * n2 + sth * n1;
    R[1][0] = omc * n1 * n0 + sth * n2;  R[1][1] = cth + omc * n1 * n1;       R[1][2] = omc * n1 * n2 - sth * n0;
    R[2][0] = omc * n2 * n0 - sth * n1;  R[2][1] = omc * n2 * n1 + sth * n0;  R[2][2] = cth + omc * n2 * n2;

    // pose-feature coefficients (R - I), row-major
    for (int rr = 0; rr < 3; ++rr)
      for (int cc = 0; cc < 3; ++cc)
        coefT[(size_t)(SDc + 9 * i + 3 * rr + cc) * Bc + b] =
            R[rr][cc] - (rr == cc ? 1.0f : 0.0f);

    // trans_n = (J[n]-J[i]) @ rot_parent + tr   (uses OLD rot)
    float d0 = J[n][0] - J[i][0], d1 = J[n][1] - J[i][1], d2 = J[n][2] - J[i][2];
    float ntr[3];
    for (int r = 0; r < 3; ++r)
      ntr[r] = d0 * rot[0][r] + d1 * rot[1][r] + d2 * rot[2][r] + tr[r];

    // rot_n = R^T @ rot_parent
    float nr[3][3];
    for (int a = 0; a < 3; ++a)
      for (int k = 0; k < 3; ++k)
        nr[a][k] = R[0][a] * rot[0][k] + R[1][a] * rot[1][k] + R[2][a] * rot[2][k];

    for (int a = 0; a < 3; ++a)
      for (int k = 0; k < 3; ++k) rot[a][k] = nr[a][k];
    tr[0] = ntr[0]; tr[1] = ntr[1]; tr[2] = ntr[2];

    float* rdn = rd + n * 12;
    for (int a = 0; a < 3; ++a)
      for (int k = 0; k < 3; ++k) rdn[a * 3 + k] = rot[a][k];
    for (int r = 0; r < 3; ++r)
      rdn[9 + r] = tr[r] - (J[n][0] * rot[0][r] + J[n][1] * rot[1][r] + J[n][2] * rot[2][r]);
  }
}

// ---------------- Kernel C: fused blendshape-GEMM + skinning ----------------
// thread = one vertex, BB=16 batches; coef/rot reads are workgroup-uniform
// (scalar loads), s_mat reads coalesced 12B/lane.
__global__ __launch_bounds__(256) void lbs_skin_kernel(
    const float* __restrict__ s_mat, const float* __restrict__ v_tmpl,
    const float* __restrict__ w_skin, const float* __restrict__ coefT,
    const float* __restrict__ rotdata, float* __restrict__ out) {
  const int v = blockIdx.x * 256 + threadIdx.x;
  const int b0 = blockIdx.y * BB;
  const bool valid = (v < Vc);
  const int vv = valid ? v : (Vc - 1);

  // v_posed accumulators, init with template
  const float t0 = v_tmpl[3 * vv + 0], t1 = v_tmpl[3 * vv + 1], t2 = v_tmpl[3 * vv + 2];
  float acc[BB][3];
#pragma unroll
  for (int bb = 0; bb < BB; ++bb) { acc[bb][0] = t0; acc[bb][1] = t1; acc[bb][2] = t2; }

  for (int k = 0; k < NC; ++k) {
    const float* sp = s_mat + (size_t)k * V3 + 3 * vv;
    const float s0 = sp[0], s1 = sp[1], s2 = sp[2];
    const float4* c4 = reinterpret_cast<const float4*>(coefT + (size_t)k * Bc + b0);
    const float4 q0 = c4[0], q1 = c4[1], q2 = c4[2], q3 = c4[3];
    const float cv[BB] = {q0.x, q0.y, q0.z, q0.w, q1.x, q1.y, q1.z, q1.w,
                          q2.x, q2.y, q2.z, q2.w, q3.x, q3.y, q3.z, q3.w};
#pragma unroll
    for (int bb = 0; bb < BB; ++bb) {
      acc[bb][0] += cv[bb] * s0;
      acc[bb][1] += cv[bb] * s1;
      acc[bb][2] += cv[bb] * s2;
    }
  }

  // skinning weights for this vertex
  float w[Pc];
#pragma unroll
  for (int p = 0; p < Pc; ++p) w[p] = w_skin[(size_t)vv * Pc + p];

#pragma unroll
  for (int bb = 0; bb < BB; ++bb) {
    const float* rd = rotdata + (size_t)(b0 + bb) * Pc * 12;
    const float vp0 = acc[bb][0], vp1 = acc[bb][1], vp2 = acc[bb][2];
    float o0 = 0.f, o1 = 0.f, o2 = 0.f;
    for (int p = 0; p < Pc; ++p) {
      const float* rp = rd + p * 12;   // uniform address -> scalar loads
      const float wp = w[p];
      o0 += wp * (vp0 * rp[0] + vp1 * rp[3] + vp2 * rp[6] + rp[9]);
      o1 += wp * (vp0 * rp[1] + vp1 * rp[4] + vp2 * rp[7] + rp[10]);
      o2 += wp * (vp0 * rp[2] + vp1 * rp[5] + vp2 * rp[8] + rp[11]);
    }
    if (valid) {
      float* op = out + ((size_t)(b0 + bb) * Vc + v) * 3;
      op[0] = o0;
      op[1] = o1;
      op[2] = o2;
    }
  }
}

extern "C" void kernel_launch(void* const* d_in, const int* in_sizes, int n_in,
                              void* d_out, int out_size, void* d_ws, size_t ws_size,
                              hipStream_t stream) {
  (void)in_sizes; (void)n_in; (void)out_size; (void)ws_size;
  const float* x      = (const float*)d_in[0];
  const float* s_mat  = (const float*)d_in[1];
  const float* v_tmpl = (const float*)d_in[2];
  const float* w_skin = (const float*)d_in[3];
  const float* j_reg  = (const float*)d_in[4];
  float* out = (float*)d_out;
  float* ws = (float*)d_ws;

  lbs_prep_kernel<<<dim3(SDc + 1, Pc), 256, 0, stream>>>(s_mat, v_tmpl, j_reg, ws + JS_OFF);
  lbs_chain_kernel<<<dim3(Bc / 256), 256, 0, stream>>>(x, ws + JS_OFF, ws + COEF_OFF, ws + ROT_OFF);
  lbs_skin_kernel<<<dim3((Vc + 255) / 256, Bc / BB), 256, 0, stream>>>(
      s_mat, v_tmpl, w_skin, ws + COEF_OFF, ws + ROT_OFF, out);
}

// Round 7
// 286.693 us; speedup vs baseline: 1.4484x; 1.4484x over previous
//
#include <hip/hip_runtime.h>
#include <hip/hip_bf16.h>

constexpr int Bc  = 1024;
constexpr int Vc  = 6890;
constexpr int Pc  = 24;
constexpr int SDc = 10;
constexpr int NJ  = Pc - 1;          // 23 rotated joints
constexpr int NC  = SDc + 9 * NJ;    // 217 coefficients
constexpr int V3  = 3 * Vc;          // 20670
constexpr int XD  = SDc + 3 * NJ;    // 79 input dims per batch

constexpr int KPAD   = 224;          // 217 padded to 7*32
constexpr int KOCT   = KPAD / 8;     // 28 k-octets
constexpr int MT     = 64;           // GEMM M tile (batch)
constexpr int NT     = 64;           // GEMM N tile (3V)
constexpr int MTILES = Bc / MT;      // 16
constexpr int NTILES = (V3 + NT - 1) / NT;  // 323
constexpr int BB2    = 16;           // batches per thread in skin pass

// ---- workspace layout (byte offsets) ----
constexpr size_t JS_BYTE   = 0;                         // 792 f32
constexpr size_t COEF_BYTE = 4096;                      // coefT [NC][B] f32 = 888832 B
constexpr size_t ROT_BYTE  = COEF_BYTE + 889856;        // rotdata [B][P][12] f32 = 1179648 B
constexpr size_t WSA_BYTE  = ROT_BYTE + 1179648 + 1024; // A bf16 blocked: 16*28*64*8*2 = 458752 B
constexpr size_t WSB_BYTE  = WSA_BYTE + 458752;         // B bf16 blocked: 323*28*64*8*2 = 9261056 B
constexpr size_t WST_BYTE  = WSB_BYTE + 9261056;        // w_skinT [P][V] f32 = 661440 B

typedef __attribute__((ext_vector_type(8))) short bf16x8;
typedef __attribute__((ext_vector_type(4))) float f32x4;

__device__ inline unsigned short bf16bits(float f) {
  union { float f; unsigned u; } x; x.f = f;
  unsigned r = x.u + 0x7fffu + ((x.u >> 16) & 1u);   // RNE
  return (unsigned short)(r >> 16);
}

// ---------------- Kernel A: batch-independent joint-regressor fold ----------
__global__ __launch_bounds__(256) void lbs_prep_kernel(
    const float* __restrict__ s_mat, const float* __restrict__ v_tmpl,
    const float* __restrict__ j_reg, float* __restrict__ ws) {
  const int d = blockIdx.x;            // 0..SD   (SD => v_tmpl row)
  const int p = blockIdx.y;            // 0..P-1
  const float* src = (d < SDc) ? (s_mat + (size_t)d * V3) : v_tmpl;
  const float* jr  = j_reg + (size_t)p * Vc;
  float a0 = 0.f, a1 = 0.f, a2 = 0.f;
  for (int v = threadIdx.x; v < Vc; v += 256) {
    float w = jr[v];
    a0 += w * src[3 * v + 0];
    a1 += w * src[3 * v + 1];
    a2 += w * src[3 * v + 2];
  }
  for (int off = 32; off > 0; off >>= 1) {
    a0 += __shfl_down(a0, off);
    a1 += __shfl_down(a1, off);
    a2 += __shfl_down(a2, off);
  }
  __shared__ float red[3][4];
  const int lane = threadIdx.x & 63, wid = threadIdx.x >> 6;
  if (lane == 0) { red[0][wid] = a0; red[1][wid] = a1; red[2][wid] = a2; }
  __syncthreads();
  if (threadIdx.x == 0) {
    float r0 = red[0][0] + red[0][1] + red[0][2] + red[0][3];
    float r1 = red[1][0] + red[1][1] + red[1][2] + red[1][3];
    float r2 = red[2][0] + red[2][1] + red[2][2] + red[2][3];
    float* dst = (d < SDc) ? (ws + ((size_t)d * Pc + p) * 3)
                           : (ws + 720 + (size_t)p * 3);
    dst[0] = r0; dst[1] = r1; dst[2] = r2;
  }
}

// ---------------- Kernel B: per-batch rodrigues + kinematic chain ----------
__global__ __launch_bounds__(256) void lbs_chain_kernel(
    const float* __restrict__ x, const float* __restrict__ ws_js,
    float* __restrict__ coefT, float* __restrict__ rotdata) {
  const int b = blockIdx.x * 256 + threadIdx.x;
  if (b >= Bc) return;
  const float* xb = x + (size_t)b * XD;

  float J[Pc][3];
  for (int p = 0; p < Pc; ++p)
    for (int c = 0; c < 3; ++c) {
      float acc = ws_js[720 + p * 3 + c];
      for (int d = 0; d < SDc; ++d) acc += xb[d] * ws_js[((size_t)d * Pc + p) * 3 + c];
      J[p][c] = acc;
    }

  for (int d = 0; d < SDc; ++d) coefT[(size_t)d * Bc + b] = xb[d];

  float rot[3][3] = {{1, 0, 0}, {0, 1, 0}, {0, 0, 1}};
  float tr[3] = {J[0][0], J[0][1], J[0][2]};
  float* rd = rotdata + (size_t)b * Pc * 12;
  rd[0] = 1; rd[1] = 0; rd[2] = 0;
  rd[3] = 0; rd[4] = 1; rd[5] = 0;
  rd[6] = 0; rd[7] = 0; rd[8] = 1;
  rd[9] = 0; rd[10] = 0; rd[11] = 0;

  for (int i = 0; i < NJ; ++i) {
    const int n = i + 1;
    float r0 = xb[SDc + 3 * i + 0], r1 = xb[SDc + 3 * i + 1], r2 = xb[SDc + 3 * i + 2];
    float th = sqrtf(r0 * r0 + r1 * r1 + r2 * r2);
    float inv = 1.0f / fmaxf(th, 1e-8f);
    float n0 = r0 * inv, n1 = r1 * inv, n2 = r2 * inv;
    float cth = cosf(th), sth = sinf(th), omc = 1.0f - cth;
    float R[3][3];
    R[0][0] = cth + omc * n0 * n0;       R[0][1] = omc * n0 * n1 - sth * n2;  R[0][2] = omc * n0 * n2 + sth * n1;
    R[1][0] = omc * n1 * n0 + sth * n2;  R[1][1] = cth + omc * n1 * n1;       R[1][2] = omc * n1 * n2 - sth * n0;
    R[2][0] = omc * n2 * n0 - sth * n1;  R[2][1] = omc * n2 * n1 + sth * n0;  R[2][2] = cth + omc * n2 * n2;

    for (int rr = 0; rr < 3; ++rr)
      for (int cc = 0; cc < 3; ++cc)
        coefT[(size_t)(SDc + 9 * i + 3 * rr + cc) * Bc + b] =
            R[rr][cc] - (rr == cc ? 1.0f : 0.0f);

    float d0 = J[n][0] - J[i][0], d1 = J[n][1] - J[i][1], d2 = J[n][2] - J[i][2];
    float ntr[3];
    for (int r = 0; r < 3; ++r)
      ntr[r] = d0 * rot[0][r] + d1 * rot[1][r] + d2 * rot[2][r] + tr[r];

    float nr[3][3];
    for (int a = 0; a < 3; ++a)
      for (int k = 0; k < 3; ++k)
        nr[a][k] = R[0][a] * rot[0][k] + R[1][a] * rot[1][k] + R[2][a] * rot[2][k];

    for (int a = 0; a < 3; ++a)
      for (int k = 0; k < 3; ++k) rot[a][k] = nr[a][k];
    tr[0] = ntr[0]; tr[1] = ntr[1]; tr[2] = ntr[2];

    float* rdn = rd + n * 12;
    for (int a = 0; a < 3; ++a)
      for (int k = 0; k < 3; ++k) rdn[a * 3 + k] = rot[a][k];
    for (int r = 0; r < 3; ++r)
      rdn[9 + r] = tr[r] - (J[n][0] * rot[0][r] + J[n][1] * rot[1][r] + J[n][2] * rot[2][r]);
  }
}

// ---------------- packB: s_mat fp32 [K][3V] -> bf16 blocked [ntile][koct][64][8] ----
__global__ __launch_bounds__(256) void lbs_packB_kernel(
    const float* __restrict__ s_mat, unsigned short* __restrict__ wsB) {
  const int idx = blockIdx.x * 256 + threadIdx.x;     // (ntile*KOCT + ko)*64 + n_local
  if (idx >= NTILES * KOCT * 64) return;
  const int n_local = idx & 63;
  const int ko = (idx >> 6) % KOCT;
  const int ntile = idx / (64 * KOCT);
  const int n = ntile * 64 + n_local;
  unsigned short v8[8];
#pragma unroll
  for (int j = 0; j < 8; ++j) {
    const int k = ko * 8 + j;
    const float f = (k < NC && n < V3) ? s_mat[(size_t)k * V3 + n] : 0.f;
    v8[j] = bf16bits(f);
  }
  *(uint4*)&wsB[(size_t)idx * 8] = *(const uint4*)v8;
}

// ---------------- packA: coefT fp32 [K][B] -> bf16 blocked [mtile][koct][64][8] ----
__global__ __launch_bounds__(256) void lbs_packA_kernel(
    const float* __restrict__ coefT, unsigned short* __restrict__ wsA) {
  const int idx = blockIdx.x * 256 + threadIdx.x;     // (mtile*KOCT + ko)*64 + m_local
  if (idx >= MTILES * KOCT * 64) return;
  const int m_local = idx & 63;
  const int ko = (idx >> 6) % KOCT;
  const int mtile = idx / (64 * KOCT);
  const int b = mtile * 64 + m_local;
  unsigned short v8[8];
#pragma unroll
  for (int j = 0; j < 8; ++j) {
    const int k = ko * 8 + j;
    const float f = (k < NC) ? coefT[(size_t)k * Bc + b] : 0.f;
    v8[j] = bf16bits(f);
  }
  *(uint4*)&wsA[(size_t)idx * 8] = *(const uint4*)v8;
}

// ---------------- w_skin [V][P] -> w_skinT [P][V] ----------------
__global__ __launch_bounds__(256) void lbs_wskinT_kernel(
    const float* __restrict__ w_skin, float* __restrict__ w_skinT) {
  const int idx = blockIdx.x * 256 + threadIdx.x;
  if (idx >= Pc * Vc) return;
  const int p = idx / Vc, v = idx % Vc;
  w_skinT[idx] = w_skin[(size_t)v * Pc + p];
}

// ---------------- MFMA GEMM: v_posed = coef @ s_mat + v_tmpl -> d_out ------
// 64x64 tile, 4 waves x (2x2 frags of 16x16x32 bf16), whole K (224) in LDS.
__global__ __launch_bounds__(256) void lbs_gemm_kernel(
    const unsigned short* __restrict__ wsA, const unsigned short* __restrict__ wsB,
    const float* __restrict__ v_tmpl, float* __restrict__ out) {
  __shared__ unsigned short lA[KPAD * MT];   // 28 KB, blocked [koct][m64][k8]
  __shared__ unsigned short lB[KPAD * NT];   // 28 KB, blocked [koct][n64][k8]
  const int mtile = blockIdx.x;
  const int ntile = blockIdx.y;
  const int t = threadIdx.x;

  const unsigned short* gA = wsA + (size_t)mtile * (KPAD * MT);
  const unsigned short* gB = wsB + (size_t)ntile * (KPAD * NT);
#pragma unroll
  for (int i = 0; i < 7; ++i) {              // 7 * 256 * 16B = 28 KB
    const uint4 a = ((const uint4*)gA)[t + i * 256];
    const uint4 b = ((const uint4*)gB)[t + i * 256];
    ((uint4*)lA)[t + i * 256] = a;
    ((uint4*)lB)[t + i * 256] = b;
  }
  __syncthreads();

  const int w = t >> 6, l = t & 63;
  const int wm = (w >> 1) * 32, wn = (w & 1) * 32;
  const int lrow = l & 15, lk = l >> 4;      // operand row/col = lrow, k-octet-lane = lk

  f32x4 acc[2][2] = {};
#pragma unroll
  for (int kk = 0; kk < 7; ++kk) {
    const int ko = kk * 4 + lk;
    const bf16x8 a0 = *(const bf16x8*)&lA[ko * 512 + (wm + lrow) * 8];
    const bf16x8 a1 = *(const bf16x8*)&lA[ko * 512 + (wm + 16 + lrow) * 8];
    const bf16x8 b0 = *(const bf16x8*)&lB[ko * 512 + (wn + lrow) * 8];
    const bf16x8 b1 = *(const bf16x8*)&lB[ko * 512 + (wn + 16 + lrow) * 8];
    acc[0][0] = __builtin_amdgcn_mfma_f32_16x16x32_bf16(a0, b0, acc[0][0], 0, 0, 0);
    acc[0][1] = __builtin_amdgcn_mfma_f32_16x16x32_bf16(a0, b1, acc[0][1], 0, 0, 0);
    acc[1][0] = __builtin_amdgcn_mfma_f32_16x16x32_bf16(a1, b0, acc[1][0], 0, 0, 0);
    acc[1][1] = __builtin_amdgcn_mfma_f32_16x16x32_bf16(a1, b1, acc[1][1], 0, 0, 0);
  }

  // C/D: col = lane&15 (n), row = (lane>>4)*4 + reg (m)   [m89-verified]
  const int nbase = ntile * 64 + wn;
  const int mbase = mtile * 64 + wm;
#pragma unroll
  for (int fn = 0; fn < 2; ++fn) {
    const int n = nbase + fn * 16 + lrow;
    if (n >= V3) continue;
    const float vt = v_tmpl[n];
#pragma unroll
    for (int fm = 0; fm < 2; ++fm) {
#pragma unroll
      for (int r = 0; r < 4; ++r) {
        const int m = mbase + fm * 16 + lk * 4 + r;
        out[(size_t)m * V3 + n] = acc[fm][fn][r] + vt;
      }
    }
  }
}

// ---------------- skin pass (in-place on d_out) ----------------
// per (b,v): A[12] = sum_p w[v,p]*T[b,p][12]; out = vp @ A_rot + A_t
__global__ __launch_bounds__(256) void lbs_skin2_kernel(
    const float* __restrict__ w_skinT, const float* __restrict__ rotdata,
    float* __restrict__ out) {
  const int v = blockIdx.x * 256 + threadIdx.x;
  const int b0 = blockIdx.y * BB2;
  if (v >= Vc) return;
  float w[Pc];
#pragma unroll
  for (int p = 0; p < Pc; ++p) w[p] = w_skinT[(size_t)p * Vc + v];   // coalesced

  for (int bb = 0; bb < BB2; ++bb) {
    const int b = b0 + bb;
    const float* rd = rotdata + (size_t)b * (Pc * 12);   // uniform -> scalar loads
    float A[12] = {0, 0, 0, 0, 0, 0, 0, 0, 0, 0, 0, 0};
#pragma unroll
    for (int p = 0; p < Pc; ++p) {
      const float wp = w[p];
      const float* rp = rd + p * 12;
#pragma unroll
      for (int q = 0; q < 12; ++q) A[q] += wp * rp[q];
    }
    float* op = out + ((size_t)b * Vc + v) * 3;
    const float vp0 = op[0], vp1 = op[1], vp2 = op[2];
    op[0] = vp0 * A[0] + vp1 * A[3] + vp2 * A[6] + A[9];
    op[1] = vp0 * A[1] + vp1 * A[4] + vp2 * A[7] + A[10];
    op[2] = vp0 * A[2] + vp1 * A[5] + vp2 * A[8] + A[11];
  }
}

extern "C" void kernel_launch(void* const* d_in, const int* in_sizes, int n_in,
                              void* d_out, int out_size, void* d_ws, size_t ws_size,
                              hipStream_t stream) {
  (void)in_sizes; (void)n_in; (void)out_size; (void)ws_size;
  const float* x      = (const float*)d_in[0];
  const float* s_mat  = (const float*)d_in[1];
  const float* v_tmpl = (const float*)d_in[2];
  const float* w_skin = (const float*)d_in[3];
  const float* j_reg  = (const float*)d_in[4];
  float* out = (float*)d_out;
  char* ws = (char*)d_ws;

  float*          js      = (float*)(ws + JS_BYTE);
  float*          coefT   = (float*)(ws + COEF_BYTE);
  float*          rotdata = (float*)(ws + ROT_BYTE);
  unsigned short* wsA     = (unsigned short*)(ws + WSA_BYTE);
  unsigned short* wsB     = (unsigned short*)(ws + WSB_BYTE);
  float*          wskT    = (float*)(ws + WST_BYTE);

  lbs_prep_kernel<<<dim3(SDc + 1, Pc), 256, 0, stream>>>(s_mat, v_tmpl, j_reg, js);
  lbs_packB_kernel<<<(NTILES * KOCT * 64 + 255) / 256, 256, 0, stream>>>(s_mat, wsB);
  lbs_wskinT_kernel<<<(Pc * Vc + 255) / 256, 256, 0, stream>>>(w_skin, wskT);
  lbs_chain_kernel<<<dim3(Bc / 256), 256, 0, stream>>>(x, js, coefT, rotdata);
  lbs_packA_kernel<<<(MTILES * KOCT * 64 + 255) / 256, 256, 0, stream>>>(coefT, wsA);
  lbs_gemm_kernel<<<dim3(MTILES, NTILES), 256, 0, stream>>>(wsA, wsB, v_tmpl, out);
  lbs_skin2_kernel<<<dim3((Vc + 255) / 256, Bc / BB2), 256, 0, stream>>>(wskT, rotdata, out);
}

// Round 8
// 267.210 us; speedup vs baseline: 1.5540x; 1.0729x over previous
//
#include <hip/hip_runtime.h>
#include <hip/hip_bf16.h>

constexpr int Bc  = 1024;
constexpr int Vc  = 6890;
constexpr int Pc  = 24;
constexpr int SDc = 10;
constexpr int NJ  = Pc - 1;          // 23 rotated joints
constexpr int NC  = SDc + 9 * NJ;    // 217 coefficients
constexpr int V3  = 3 * Vc;          // 20670
constexpr int XD  = SDc + 3 * NJ;    // 79 input dims per batch

constexpr int KPAD   = 224;          // 217 padded to 7*32
constexpr int KOCT   = KPAD / 8;     // 28 k-octets
constexpr int MT     = 64;           // GEMM M tile (batch)
constexpr int NT     = 64;           // GEMM N tile (3V)
constexpr int MTILES = Bc / MT;      // 16
constexpr int NTILES = (V3 + NT - 1) / NT;  // 323
constexpr int BB2    = 16;           // batches per block in skin pass

// ---- workspace layout (byte offsets) ----
constexpr size_t JS_BYTE   = 0;                         // 792 f32
constexpr size_t COEF_BYTE = 4096;                      // coefT [NC][B] f32 = 888832 B
constexpr size_t ROT_BYTE  = COEF_BYTE + 889856;        // rotdata [B][P][12] f32 = 1179648 B
constexpr size_t WSA_BYTE  = ROT_BYTE + 1179648 + 1024; // A bf16 blocked: 16*28*64*8*2 = 458752 B
constexpr size_t WSB_BYTE  = WSA_BYTE + 458752;         // B bf16 blocked: 323*28*64*8*2 = 9261056 B
constexpr size_t WST_BYTE  = WSB_BYTE + 9261056;        // w_skinT [P][V] f32 = 661440 B

typedef __attribute__((ext_vector_type(8))) short bf16x8;
typedef __attribute__((ext_vector_type(4))) float f32x4;

__device__ inline unsigned short bf16bits(float f) {
  union { float f; unsigned u; } x; x.f = f;
  unsigned r = x.u + 0x7fffu + ((x.u >> 16) & 1u);   // RNE
  return (unsigned short)(r >> 16);
}

// ---------------- Kernel A: batch-independent joint-regressor fold ----------
__global__ __launch_bounds__(256) void lbs_prep_kernel(
    const float* __restrict__ s_mat, const float* __restrict__ v_tmpl,
    const float* __restrict__ j_reg, float* __restrict__ ws) {
  const int d = blockIdx.x;            // 0..SD   (SD => v_tmpl row)
  const int p = blockIdx.y;            // 0..P-1
  const float* src = (d < SDc) ? (s_mat + (size_t)d * V3) : v_tmpl;
  const float* jr  = j_reg + (size_t)p * Vc;
  float a0 = 0.f, a1 = 0.f, a2 = 0.f;
  for (int v = threadIdx.x; v < Vc; v += 256) {
    float w = jr[v];
    a0 += w * src[3 * v + 0];
    a1 += w * src[3 * v + 1];
    a2 += w * src[3 * v + 2];
  }
  for (int off = 32; off > 0; off >>= 1) {
    a0 += __shfl_down(a0, off);
    a1 += __shfl_down(a1, off);
    a2 += __shfl_down(a2, off);
  }
  __shared__ float red[3][4];
  const int lane = threadIdx.x & 63, wid = threadIdx.x >> 6;
  if (lane == 0) { red[0][wid] = a0; red[1][wid] = a1; red[2][wid] = a2; }
  __syncthreads();
  if (threadIdx.x == 0) {
    float r0 = red[0][0] + red[0][1] + red[0][2] + red[0][3];
    float r1 = red[1][0] + red[1][1] + red[1][2] + red[1][3];
    float r2 = red[2][0] + red[2][1] + red[2][2] + red[2][3];
    float* dst = (d < SDc) ? (ws + ((size_t)d * Pc + p) * 3)
                           : (ws + 720 + (size_t)p * 3);
    dst[0] = r0; dst[1] = r1; dst[2] = r2;
  }
}

// ---------------- Kernel B: per-batch rodrigues + kinematic chain ----------
// LDS-staged ws_js (uniform s_loads serialized on lgkmcnt; ds_read pipelines).
// 16 blocks x 64 threads so 16 CUs participate.
__global__ __launch_bounds__(64) void lbs_chain_kernel(
    const float* __restrict__ x, const float* __restrict__ ws_js,
    float* __restrict__ coefT, float* __restrict__ rotdata) {
  __shared__ float js[792];
  const int t = threadIdx.x;
  for (int i = t; i < 792; i += 64) js[i] = ws_js[i];
  __syncthreads();

  const int b = blockIdx.x * 64 + t;
  const float* xb = x + (size_t)b * XD;

  float xs[SDc];
#pragma unroll
  for (int d = 0; d < SDc; ++d) xs[d] = xb[d];

  float J[Pc][3];
#pragma unroll
  for (int p = 0; p < Pc; ++p)
#pragma unroll
    for (int c = 0; c < 3; ++c) {
      float acc = js[720 + p * 3 + c];
#pragma unroll
      for (int d = 0; d < SDc; ++d) acc += xs[d] * js[(d * Pc + p) * 3 + c];
      J[p][c] = acc;
    }

  for (int d = 0; d < SDc; ++d) coefT[(size_t)d * Bc + b] = xs[d];

  float rot[3][3] = {{1, 0, 0}, {0, 1, 0}, {0, 0, 1}};
  float tr[3] = {J[0][0], J[0][1], J[0][2]};
  float* rd = rotdata + (size_t)b * Pc * 12;
  rd[0] = 1; rd[1] = 0; rd[2] = 0;
  rd[3] = 0; rd[4] = 1; rd[5] = 0;
  rd[6] = 0; rd[7] = 0; rd[8] = 1;
  rd[9] = 0; rd[10] = 0; rd[11] = 0;

  for (int i = 0; i < NJ; ++i) {
    const int n = i + 1;
    float r0 = xb[SDc + 3 * i + 0], r1 = xb[SDc + 3 * i + 1], r2 = xb[SDc + 3 * i + 2];
    float th = sqrtf(r0 * r0 + r1 * r1 + r2 * r2);
    float inv = 1.0f / fmaxf(th, 1e-8f);
    float n0 = r0 * inv, n1 = r1 * inv, n2 = r2 * inv;
    float cth = cosf(th), sth = sinf(th), omc = 1.0f - cth;
    float R[3][3];
    R[0][0] = cth + omc * n0 * n0;       R[0][1] = omc * n0 * n1 - sth * n2;  R[0][2] = omc * n0 * n2 + sth * n1;
    R[1][0] = omc * n1 * n0 + sth * n2;  R[1][1] = cth + omc * n1 * n1;       R[1][2] = omc * n1 * n2 - sth * n0;
    R[2][0] = omc * n2 * n0 - sth * n1;  R[2][1] = omc * n2 * n1 + sth * n0;  R[2][2] = cth + omc * n2 * n2;

    for (int rr = 0; rr < 3; ++rr)
      for (int cc = 0; cc < 3; ++cc)
        coefT[(size_t)(SDc + 9 * i + 3 * rr + cc) * Bc + b] =
            R[rr][cc] - (rr == cc ? 1.0f : 0.0f);

    float d0 = J[n][0] - J[i][0], d1 = J[n][1] - J[i][1], d2 = J[n][2] - J[i][2];
    float ntr[3];
    for (int r = 0; r < 3; ++r)
      ntr[r] = d0 * rot[0][r] + d1 * rot[1][r] + d2 * rot[2][r] + tr[r];

    float nr[3][3];
    for (int a = 0; a < 3; ++a)
      for (int k = 0; k < 3; ++k)
        nr[a][k] = R[0][a] * rot[0][k] + R[1][a] * rot[1][k] + R[2][a] * rot[2][k];

    for (int a = 0; a < 3; ++a)
      for (int k = 0; k < 3; ++k) rot[a][k] = nr[a][k];
    tr[0] = ntr[0]; tr[1] = ntr[1]; tr[2] = ntr[2];

    float* rdn = rd + n * 12;
    for (int a = 0; a < 3; ++a)
      for (int k = 0; k < 3; ++k) rdn[a * 3 + k] = rot[a][k];
    for (int r = 0; r < 3; ++r)
      rdn[9 + r] = tr[r] - (J[n][0] * rot[0][r] + J[n][1] * rot[1][r] + J[n][2] * rot[2][r]);
  }
}

// ---------------- packB: s_mat fp32 [K][3V] -> bf16 blocked [ntile][koct][64][8] ----
__global__ __launch_bounds__(256) void lbs_packB_kernel(
    const float* __restrict__ s_mat, unsigned short* __restrict__ wsB) {
  const int idx = blockIdx.x * 256 + threadIdx.x;     // (ntile*KOCT + ko)*64 + n_local
  if (idx >= NTILES * KOCT * 64) return;
  const int n_local = idx & 63;
  const int ko = (idx >> 6) % KOCT;
  const int ntile = idx / (64 * KOCT);
  const int n = ntile * 64 + n_local;
  unsigned short v8[8];
#pragma unroll
  for (int j = 0; j < 8; ++j) {
    const int k = ko * 8 + j;
    const float f = (k < NC && n < V3) ? s_mat[(size_t)k * V3 + n] : 0.f;
    v8[j] = bf16bits(f);
  }
  *(uint4*)&wsB[(size_t)idx * 8] = *(const uint4*)v8;
}

// ---------------- packA: coefT fp32 [K][B] -> bf16 blocked [mtile][koct][64][8] ----
__global__ __launch_bounds__(256) void lbs_packA_kernel(
    const float* __restrict__ coefT, unsigned short* __restrict__ wsA) {
  const int idx = blockIdx.x * 256 + threadIdx.x;     // (mtile*KOCT + ko)*64 + m_local
  if (idx >= MTILES * KOCT * 64) return;
  const int m_local = idx & 63;
  const int ko = (idx >> 6) % KOCT;
  const int mtile = idx / (64 * KOCT);
  const int b = mtile * 64 + m_local;
  unsigned short v8[8];
#pragma unroll
  for (int j = 0; j < 8; ++j) {
    const int k = ko * 8 + j;
    const float f = (k < NC) ? coefT[(size_t)k * Bc + b] : 0.f;
    v8[j] = bf16bits(f);
  }
  *(uint4*)&wsA[(size_t)idx * 8] = *(const uint4*)v8;
}

// ---------------- w_skin [V][P] -> w_skinT [P][V] ----------------
__global__ __launch_bounds__(256) void lbs_wskinT_kernel(
    const float* __restrict__ w_skin, float* __restrict__ w_skinT) {
  const int idx = blockIdx.x * 256 + threadIdx.x;
  if (idx >= Pc * Vc) return;
  const int p = idx / Vc, v = idx % Vc;
  w_skinT[idx] = w_skin[(size_t)v * Pc + p];
}

// ---------------- MFMA GEMM: v_posed = coef @ s_mat + v_tmpl -> d_out ------
__global__ __launch_bounds__(256) void lbs_gemm_kernel(
    const unsigned short* __restrict__ wsA, const unsigned short* __restrict__ wsB,
    const float* __restrict__ v_tmpl, float* __restrict__ out) {
  __shared__ unsigned short lA[KPAD * MT];   // 28 KB, blocked [koct][m64][k8]
  __shared__ unsigned short lB[KPAD * NT];   // 28 KB, blocked [koct][n64][k8]
  const int mtile = blockIdx.x;
  const int ntile = blockIdx.y;
  const int t = threadIdx.x;

  const unsigned short* gA = wsA + (size_t)mtile * (KPAD * MT);
  const unsigned short* gB = wsB + (size_t)ntile * (KPAD * NT);
#pragma unroll
  for (int i = 0; i < 7; ++i) {              // 7 * 256 * 16B = 28 KB
    const uint4 a = ((const uint4*)gA)[t + i * 256];
    const uint4 b = ((const uint4*)gB)[t + i * 256];
    ((uint4*)lA)[t + i * 256] = a;
    ((uint4*)lB)[t + i * 256] = b;
  }
  __syncthreads();

  const int w = t >> 6, l = t & 63;
  const int wm = (w >> 1) * 32, wn = (w & 1) * 32;
  const int lrow = l & 15, lk = l >> 4;

  f32x4 acc[2][2] = {};
#pragma unroll
  for (int kk = 0; kk < 7; ++kk) {
    const int ko = kk * 4 + lk;
    const bf16x8 a0 = *(const bf16x8*)&lA[ko * 512 + (wm + lrow) * 8];
    const bf16x8 a1 = *(const bf16x8*)&lA[ko * 512 + (wm + 16 + lrow) * 8];
    const bf16x8 b0 = *(const bf16x8*)&lB[ko * 512 + (wn + lrow) * 8];
    const bf16x8 b1 = *(const bf16x8*)&lB[ko * 512 + (wn + 16 + lrow) * 8];
    acc[0][0] = __builtin_amdgcn_mfma_f32_16x16x32_bf16(a0, b0, acc[0][0], 0, 0, 0);
    acc[0][1] = __builtin_amdgcn_mfma_f32_16x16x32_bf16(a0, b1, acc[0][1], 0, 0, 0);
    acc[1][0] = __builtin_amdgcn_mfma_f32_16x16x32_bf16(a1, b0, acc[1][0], 0, 0, 0);
    acc[1][1] = __builtin_amdgcn_mfma_f32_16x16x32_bf16(a1, b1, acc[1][1], 0, 0, 0);
  }

  const int nbase = ntile * 64 + wn;
  const int mbase = mtile * 64 + wm;
#pragma unroll
  for (int fn = 0; fn < 2; ++fn) {
    const int n = nbase + fn * 16 + lrow;
    if (n >= V3) continue;
    const float vt = v_tmpl[n];
#pragma unroll
    for (int fm = 0; fm < 2; ++fm) {
#pragma unroll
      for (int r = 0; r < 4; ++r) {
        const int m = mbase + fm * 16 + lk * 4 + r;
        out[(size_t)m * V3 + n] = acc[fm][fn][r] + vt;
      }
    }
  }
}

// ---------------- skin pass (in-place on d_out), LDS-staged rotdata --------
__global__ __launch_bounds__(256) void lbs_skin2_kernel(
    const float* __restrict__ w_skinT, const float* __restrict__ rotdata,
    float* __restrict__ out) {
  __shared__ __align__(16) float rl[BB2 * Pc * 12];   // 18432 B
  const int t = threadIdx.x;
  const int b0 = blockIdx.y * BB2;
  for (int i = t; i < BB2 * Pc * 12; i += 256)        // coalesced stage
    rl[i] = rotdata[(size_t)b0 * (Pc * 12) + i];
  __syncthreads();

  const int v = blockIdx.x * 256 + t;
  if (v >= Vc) return;
  float w[Pc];
#pragma unroll
  for (int p = 0; p < Pc; ++p) w[p] = w_skinT[(size_t)p * Vc + v];   // coalesced

  for (int bb = 0; bb < BB2; ++bb) {
    const float* rb = rl + bb * (Pc * 12);
    float4 A0 = {0, 0, 0, 0}, A1 = {0, 0, 0, 0}, A2 = {0, 0, 0, 0};
#pragma unroll
    for (int p = 0; p < Pc; ++p) {
      const float wp = w[p];
      const float4 r0 = *(const float4*)&rb[p * 12 + 0];
      const float4 r1 = *(const float4*)&rb[p * 12 + 4];
      const float4 r2 = *(const float4*)&rb[p * 12 + 8];
      A0.x += wp * r0.x; A0.y += wp * r0.y; A0.z += wp * r0.z; A0.w += wp * r0.w;
      A1.x += wp * r1.x; A1.y += wp * r1.y; A1.z += wp * r1.z; A1.w += wp * r1.w;
      A2.x += wp * r2.x; A2.y += wp * r2.y; A2.z += wp * r2.z; A2.w += wp * r2.w;
    }
    float* op = out + ((size_t)(b0 + bb) * Vc + v) * 3;
    const float vp0 = op[0], vp1 = op[1], vp2 = op[2];
    // A-layout: [0..8] rot row-major, [9..11] t_adj
    op[0] = vp0 * A0.x + vp1 * A0.w + vp2 * A1.z + A2.y;
    op[1] = vp0 * A0.y + vp1 * A1.x + vp2 * A1.w + A2.z;
    op[2] = vp0 * A0.z + vp1 * A1.y + vp2 * A2.x + A2.w;
  }
}

extern "C" void kernel_launch(void* const* d_in, const int* in_sizes, int n_in,
                              void* d_out, int out_size, void* d_ws, size_t ws_size,
                              hipStream_t stream) {
  (void)in_sizes; (void)n_in; (void)out_size; (void)ws_size;
  const float* x      = (const float*)d_in[0];
  const float* s_mat  = (const float*)d_in[1];
  const float* v_tmpl = (const float*)d_in[2];
  const float* w_skin = (const float*)d_in[3];
  const float* j_reg  = (const float*)d_in[4];
  float* out = (float*)d_out;
  char* ws = (char*)d_ws;

  float*          js      = (float*)(ws + JS_BYTE);
  float*          coefT   = (float*)(ws + COEF_BYTE);
  float*          rotdata = (float*)(ws + ROT_BYTE);
  unsigned short* wsA     = (unsigned short*)(ws + WSA_BYTE);
  unsigned short* wsB     = (unsigned short*)(ws + WSB_BYTE);
  float*          wskT    = (float*)(ws + WST_BYTE);

  lbs_prep_kernel<<<dim3(SDc + 1, Pc), 256, 0, stream>>>(s_mat, v_tmpl, j_reg, js);
  lbs_packB_kernel<<<(NTILES * KOCT * 64 + 255) / 256, 256, 0, stream>>>(s_mat, wsB);
  lbs_wskinT_kernel<<<(Pc * Vc + 255) / 256, 256, 0, stream>>>(w_skin, wskT);
  lbs_chain_kernel<<<dim3(Bc / 64), 64, 0, stream>>>(x, js, coefT, rotdata);
  lbs_packA_kernel<<<(MTILES * KOCT * 64 + 255) / 256, 256, 0, stream>>>(coefT, wsA);
  lbs_gemm_kernel<<<dim3(MTILES, NTILES), 256, 0, stream>>>(wsA, wsB, v_tmpl, out);
  lbs_skin2_kernel<<<dim3((Vc + 255) / 256, Bc / BB2), 256, 0, stream>>>(wskT, rotdata, out);
}